// Round 14
// baseline (342.406 us; speedup 1.0000x reference)
//
#include <hip/hip_runtime.h>
#include <math.h>

#define T 2048
#define D 512
#define NH 8
#define DH 64
#define NB 4
#define NTOK (NB * T)   // 8192
#define LOG2E 1.44269504f
#define QSCALE (0.125f * LOG2E)

using bf16x8 = __attribute__((ext_vector_type(8))) short;
using f32x4  = __attribute__((ext_vector_type(4))) float;

static __device__ __forceinline__ unsigned short f2bf(float f) {
    union { float f; unsigned u; } v; v.f = f;
    unsigned r = v.u + 0x7fffu + ((v.u >> 16) & 1u);   // RNE
    return (unsigned short)(r >> 16);
}
#if __has_builtin(__builtin_amdgcn_cvt_pk_bf16_f32)
static __device__ __forceinline__ unsigned pack_bf16_pair(float a, float b) {
    auto r = __builtin_amdgcn_cvt_pk_bf16_f32(a, b);
    union { decltype(r) v; unsigned u; } c; c.v = r;
    return c.u;
}
#else
static __device__ __forceinline__ unsigned pack_bf16_pair(float a, float b) {
    union { float f; unsigned u; } ua, ub; ua.f = a; ub.f = b;
    unsigned ra = ua.u + 0x7fffu + ((ua.u >> 16) & 1u);
    unsigned rb = ub.u + 0x7fffu + ((ub.u >> 16) & 1u);
    return __builtin_amdgcn_perm(rb, ra, 0x07060302);
}
#endif

// Fragment layouts (lane = quad*16+lm, 8 bf16 per lane, 1 KB per chunk):
// xfrag  A-frag: chunk = t16*16 + kc           elem = x[t16*16+lm][kc*32+quad*8+e]
// wbfrag B-frag: chunk = j16*16 + kc           elem = W[j16*16+lm][kc*32+quad*8+e]
// qfrag  A-frag: chunk = (bh*128+t16)*2+kk     elem = q[t16*16+lm][kk*32+quad*8+e]
// kfrag  B-frag: chunk = ((bh*32+t64)*2+kk)*4+nt  elem = k[key=t64*64+lm*4+nt][kk*32+quad*8+e]
// vfrag  B-frag: chunk = ((bh*32+t64)*2+kk)*5+nt  elem = v'[dh=nt*16+lm][key=t64*64+kk*32+quad*8+e]
//        (nt=4 column of vfrag = w-vector for l-via-MFMA; v' = w*v)

// ---------------- Kernel A: prep = LayerNorm (blocks 0..511) + Wconv (512..607)
__global__ __launch_bounds__(256) void prep_kernel(
    const float* __restrict__ embs, const float* __restrict__ labels,
    const float* __restrict__ g, const float* __restrict__ bb,
    const float* __restrict__ alpha_p, const float* __restrict__ beta_p,
    const float* __restrict__ w,
    unsigned short* __restrict__ xfrag, unsigned short* __restrict__ wbfrag,
    float* __restrict__ wexp, float* __restrict__ kpmf)
{
    __shared__ __align__(16) unsigned short Xs[16][520];
    int tid = threadIdx.x, wave = tid >> 6, lane = tid & 63;
    int quad = lane >> 4, lm = lane & 15;

    if (blockIdx.x < 512) {
        int t16 = blockIdx.x;
        float4 g0 = *(const float4*)(g + lane * 8), g1 = *(const float4*)(g + lane * 8 + 4);
        float4 c0 = *(const float4*)(bb + lane * 8), c1 = *(const float4*)(bb + lane * 8 + 4);
        float gv[8] = {g0.x, g0.y, g0.z, g0.w, g1.x, g1.y, g1.z, g1.w};
        float cv[8] = {c0.x, c0.y, c0.z, c0.w, c1.x, c1.y, c1.z, c1.w};

        for (int tt = 0; tt < 4; ++tt) {
            int n = t16 * 16 + wave * 4 + tt;
            const float* e = embs + (size_t)n * D + lane * 8;
            float4 a4 = *(const float4*)e, b4 = *(const float4*)(e + 4);
            float v[8] = {a4.x, a4.y, a4.z, a4.w, b4.x, b4.y, b4.z, b4.w};

            float s = 0.f, ss = 0.f;
            #pragma unroll
            for (int j = 0; j < 8; ++j) { s += v[j]; ss += v[j] * v[j]; }
            #pragma unroll
            for (int o = 1; o <= 32; o <<= 1) {
                s += __shfl_xor(s, o, 64);
                ss += __shfl_xor(ss, o, 64);
            }
            float mu = s * (1.0f / D);
            float var = ss * (1.0f / D) - mu * mu;
            float rstd = rsqrtf(var + 1e-5f);

            float x[8], as = 0.f;
            #pragma unroll
            for (int j = 0; j < 8; ++j) {
                x[j] = (v[j] - mu) * rstd * gv[j] + cv[j];
                as += fabsf(x[j]);
            }
            uint4 pk;
            pk.x = pack_bf16_pair(x[0], x[1]);
            pk.y = pack_bf16_pair(x[2], x[3]);
            pk.z = pack_bf16_pair(x[4], x[5]);
            pk.w = pack_bf16_pair(x[6], x[7]);
            *(uint4*)&Xs[wave * 4 + tt][lane * 8] = pk;

            #pragma unroll
            for (int o = 1; o <= 32; o <<= 1) as += __shfl_xor(as, o, 64);
            if (lane == 0) {
                int kpm = (as <= 1e-6f);
                kpmf[n] = kpm ? 1.0f : 0.0f;
                wexp[n] = kpm ? 0.0f : __expf(alpha_p[0] * labels[n] + beta_p[0]);
            }
        }
        __syncthreads();
        #pragma unroll
        for (int i = 0; i < 4; ++i) {
            int kc = wave * 4 + i;
            bf16x8 fr = *(const bf16x8*)&Xs[lm][kc * 32 + quad * 8];
            *(bf16x8*)(xfrag + ((size_t)(t16 * 16 + kc) * 64 + lane) * 8) = fr;
        }
    } else {
        int j16 = blockIdx.x - 512;
        for (int tt = 0; tt < 4; ++tt) {
            int j = j16 * 16 + wave * 4 + tt;
            const float* wp = w + (size_t)j * D + lane * 8;
            float4 a4 = *(const float4*)wp, b4 = *(const float4*)(wp + 4);
            uint4 pk;
            pk.x = pack_bf16_pair(a4.x, a4.y);
            pk.y = pack_bf16_pair(a4.z, a4.w);
            pk.z = pack_bf16_pair(b4.x, b4.y);
            pk.w = pack_bf16_pair(b4.z, b4.w);
            *(uint4*)&Xs[wave * 4 + tt][lane * 8] = pk;
        }
        __syncthreads();
        #pragma unroll
        for (int i = 0; i < 4; ++i) {
            int kc = wave * 4 + i;
            bf16x8 fr = *(const bf16x8*)&Xs[lm][kc * 32 + quad * 8];
            *(bf16x8*)(wbfrag + ((size_t)(j16 * 16 + kc) * 64 + lane) * 8) = fr;
        }
    }
}

// ---------------- Kernel B: QKV projection, all-coalesced, pipelined --------
// V-blocks also fill the vfrag nt=4 w-columns for their (bh, t64, kk).
__global__ __launch_bounds__(256) void qkv_mfma(
    const unsigned short* __restrict__ xfrag, const unsigned short* __restrict__ wbfrag,
    const float* __restrict__ bias, const float* __restrict__ wexp,
    unsigned short* __restrict__ qfrag, unsigned short* __restrict__ kfrag,
    unsigned short* __restrict__ vfrag)
{
    __shared__ __align__(16) unsigned short Ls[4][64][72];
    int tid = threadIdx.x;
    int wave = tid >> 6, lane = tid & 63, quad = lane >> 4, lm = lane & 15;
    int wr = wave >> 1, wc = wave & 1;
    int m0 = blockIdx.x * 128 + wr * 64;
    int j0 = blockIdx.y * 128 + wc * 64;
    int mt16 = m0 >> 4, jt16 = j0 >> 4;

    f32x4 acc[4][4];
    #pragma unroll
    for (int a = 0; a < 4; ++a)
        #pragma unroll
        for (int b = 0; b < 4; ++b) acc[a][b] = (f32x4){0.f,0.f,0.f,0.f};

    bf16x8 af0[4], bf0[4], af1[4], bf1[4];
    auto load_ab = [&](int kc, bf16x8 (&af)[4], bf16x8 (&bf)[4]) {
        #pragma unroll
        for (int mf = 0; mf < 4; ++mf)
            af[mf] = *(const bf16x8*)(xfrag + ((size_t)((mt16 + mf) * 16 + kc) * 64 + lane) * 8);
        #pragma unroll
        for (int nt = 0; nt < 4; ++nt)
            bf[nt] = *(const bf16x8*)(wbfrag + ((size_t)((jt16 + nt) * 16 + kc) * 64 + lane) * 8);
    };
    auto do_mfma = [&](bf16x8 (&af)[4], bf16x8 (&bf)[4]) {
        #pragma unroll
        for (int mf = 0; mf < 4; ++mf)
            #pragma unroll
            for (int nt = 0; nt < 4; ++nt)
                acc[mf][nt] = __builtin_amdgcn_mfma_f32_16x16x32_bf16(af[mf], bf[nt], acc[mf][nt], 0, 0, 0);
    };

    load_ab(0, af0, bf0);
    for (int kc = 0; kc < 16; kc += 2) {
        load_ab(kc + 1, af1, bf1);
        do_mfma(af0, bf0);
        load_ab((kc + 2) & 15, af0, bf0);   // phantom wrap reload on last iter
        do_mfma(af1, bf1);
    }

    int part = j0 >> 9;            // 0=q,1=k,2=v
    int h = (j0 & 511) >> 6;
    int b_ = m0 >> 11, tloc = m0 & (T - 1);
    int bh = b_ * NH + h;
    float bcol[4];
    #pragma unroll
    for (int nt = 0; nt < 4; ++nt) bcol[nt] = bias[j0 + nt * 16 + lm];

    if (part == 2) {
        // V' = w*V; LDS [dh][key]; C-layout r-runs contiguous -> b64 writes
        float wv[4][4];
        #pragma unroll
        for (int mf = 0; mf < 4; ++mf)
            #pragma unroll
            for (int r = 0; r < 4; ++r)
                wv[mf][r] = wexp[b_ * T + tloc + mf * 16 + quad * 4 + r];
        #pragma unroll
        for (int mf = 0; mf < 4; ++mf)
            #pragma unroll
            for (int nt = 0; nt < 4; ++nt) {
                uint2 pw;
                pw.x = pack_bf16_pair((acc[mf][nt][0] + bcol[nt]) * wv[mf][0],
                                      (acc[mf][nt][1] + bcol[nt]) * wv[mf][1]);
                pw.y = pack_bf16_pair((acc[mf][nt][2] + bcol[nt]) * wv[mf][2],
                                      (acc[mf][nt][3] + bcol[nt]) * wv[mf][3]);
                *(uint2*)&Ls[wave][nt * 16 + lm][mf * 16 + quad * 4] = pw;
            }
        #pragma unroll
        for (int nt = 0; nt < 4; ++nt)
            #pragma unroll
            for (int kk = 0; kk < 2; ++kk) {
                bf16x8 fr = *(const bf16x8*)&Ls[wave][nt * 16 + lm][kk * 32 + quad * 8];
                size_t chunk = ((((size_t)bh * 32 + (tloc >> 6)) * 2 + kk) * 5) + nt;
                *(bf16x8*)(vfrag + chunk * 512 + lane * 8) = fr;
            }
        // w-column fill: block covers heads {hbase,hbase+1} x t64 {t64base,t64base+1};
        // wave (hsel=wave&1, tsel=wave>>1) owns one (h', t64') -- BLOCK-base derived.
        {
            int hsel = wave & 1, tsel = wave >> 1;
            int hbase = ((blockIdx.y * 128) & 511) >> 6;
            int t64base = ((blockIdx.x * 128) & (T - 1)) >> 6;
            int bh2 = b_ * NH + hbase + hsel;
            int t64a = t64base + tsel;
            #pragma unroll
            for (int kk = 0; kk < 2; ++kk) {
                size_t chunk = ((((size_t)bh2 * 32 + t64a) * 2 + kk) * 5) + 4;
                uint4 pk = {0u, 0u, 0u, 0u};
                if (lm == 0) {
                    const float* wp = wexp + b_ * T + t64a * 64 + kk * 32 + quad * 8;
                    unsigned short vv[8];
                    #pragma unroll
                    for (int e = 0; e < 8; ++e) vv[e] = f2bf(wp[e]);
                    pk = *(uint4*)vv;
                }
                *(uint4*)(vfrag + chunk * 512 + lane * 8) = pk;
            }
        }
    } else {
        // LDS [token][dh]; scalar b16 writes (one-time), b128 frag reads
        float scale = (part == 0) ? QSCALE : 1.0f;
        #pragma unroll
        for (int mf = 0; mf < 4; ++mf)
            #pragma unroll
            for (int nt = 0; nt < 4; ++nt)
                #pragma unroll
                for (int r = 0; r < 4; ++r)
                    Ls[wave][mf * 16 + quad * 4 + r][nt * 16 + lm] =
                        f2bf((acc[mf][nt][r] + bcol[nt]) * scale);
        if (part == 0) {
            #pragma unroll
            for (int mf = 0; mf < 4; ++mf)
                #pragma unroll
                for (int kk = 0; kk < 2; ++kk) {
                    bf16x8 fr = *(const bf16x8*)&Ls[wave][mf * 16 + lm][kk * 32 + quad * 8];
                    size_t chunk = ((size_t)bh * 128 + (tloc >> 4) + mf) * 2 + kk;
                    *(bf16x8*)(qfrag + chunk * 512 + lane * 8) = fr;
                }
        } else {
            #pragma unroll
            for (int nta = 0; nta < 4; ++nta)
                #pragma unroll
                for (int kk = 0; kk < 2; ++kk) {
                    bf16x8 fr = *(const bf16x8*)&Ls[wave][lm * 4 + nta][kk * 32 + quad * 8];
                    size_t chunk = ((((size_t)bh * 32 + (tloc >> 6)) * 2 + kk) * 4) + nta;
                    *(bf16x8*)(kfrag + chunk * 512 + lane * 8) = fr;
                }
        }
    }
}

// ---------------- Kernel C: flash attention, 2x4 wave specialization --------
// 512 threads = 8 waves: (qh = wave>>2) x (ks = wave&3). Grid 512 (2/CU ->
// 16 waves/CU = 4/SIMD). Wave: 64 queries x 512 keys (8 tiles). Max-free
// exp2 softmax; l additive across key-quarters via one LDS exchange.
__global__ __launch_bounds__(512, 4) void attn_mfma(
    const unsigned short* __restrict__ qfrag, const unsigned short* __restrict__ kfrag,
    const unsigned short* __restrict__ vfrag, const float* __restrict__ kpmf,
    float* __restrict__ S)
{
    __shared__ __align__(16) unsigned short Ps[8][64][72];   // per-wave P
    __shared__ float Lx[2][4][64];                           // [qh][ks][row]
    int g = blockIdx.x;
    int bh = g & 31, q0 = (g >> 5) * 128;
    int tid = threadIdx.x, wave = tid >> 6, lane = tid & 63;
    int quad = lane >> 4, lm = lane & 15;
    int qh = wave >> 2, ks = wave & 3;
    int qbase = q0 + qh * 64;
    int b_ = bh >> 3, h = bh & 7;

    bf16x8 qf[4][2];
    int t16b = (qbase >> 4);
    #pragma unroll
    for (int mf = 0; mf < 4; ++mf)
        #pragma unroll
        for (int kk = 0; kk < 2; ++kk)
            qf[mf][kk] = *(const bf16x8*)(qfrag +
                (((size_t)(bh * 128 + t16b + mf) * 2 + kk) * 64 + lane) * 8);

    f32x4 accO[4][4], accL[4];
    #pragma unroll
    for (int mf = 0; mf < 4; ++mf) {
        #pragma unroll
        for (int nt = 0; nt < 4; ++nt) accO[mf][nt] = (f32x4){0.f,0.f,0.f,0.f};
        accL[mf] = (f32x4){0.f,0.f,0.f,0.f};
    }

    const unsigned short* kb = kfrag + (size_t)bh * 32 * 8 * 512 + (size_t)lane * 8;
    const unsigned short* vb = vfrag + (size_t)bh * 32 * 10 * 512 + (size_t)lane * 8;
    int t0k = ks * 8;   // wave's 8 key-tiles

    bf16x8 kf0[4][2], kf1[4][2];
    auto load_k = [&](int t64, bf16x8 (&kf)[4][2]) {
        const unsigned short* p = kb + (size_t)t64 * 8 * 512;
        #pragma unroll
        for (int kk = 0; kk < 2; ++kk)
            #pragma unroll
            for (int nt = 0; nt < 4; ++nt)
                kf[nt][kk] = *(const bf16x8*)(p + ((size_t)kk * 4 + nt) * 512);
    };

    auto process = [&](int t64, bf16x8 (&kf)[4][2]) {
        const unsigned short* p = vb + (size_t)t64 * 10 * 512;
        bf16x8 vf[5][2];
        #pragma unroll
        for (int kk = 0; kk < 2; ++kk)
            #pragma unroll
            for (int nt = 0; nt < 5; ++nt)
                vf[nt][kk] = *(const bf16x8*)(p + ((size_t)kk * 5 + nt) * 512);

        #pragma unroll
        for (int mf = 0; mf < 4; ++mf) {
            f32x4 s[4];
            #pragma unroll
            for (int nt = 0; nt < 4; ++nt) {
                f32x4 t0 = (f32x4){0.f,0.f,0.f,0.f};
                t0 = __builtin_amdgcn_mfma_f32_16x16x32_bf16(qf[mf][0], kf[nt][0], t0, 0, 0, 0);
                t0 = __builtin_amdgcn_mfma_f32_16x16x32_bf16(qf[mf][1], kf[nt][1], t0, 0, 0, 0);
                s[nt] = t0;
            }
            int rowb = mf * 16 + quad * 4;
            #pragma unroll
            for (int r = 0; r < 4; ++r) {
                float p0 = __builtin_amdgcn_exp2f(s[0][r]);
                float p1 = __builtin_amdgcn_exp2f(s[1][r]);
                float p2 = __builtin_amdgcn_exp2f(s[2][r]);
                float p3 = __builtin_amdgcn_exp2f(s[3][r]);
                uint2 pw;
                pw.x = pack_bf16_pair(p0, p1);
                pw.y = pack_bf16_pair(p2, p3);
                *(uint2*)&Ps[wave][rowb + r][lm * 4] = pw;
            }
        }

        bf16x8 pf[4][2];
        #pragma unroll
        for (int mf = 0; mf < 4; ++mf)
            #pragma unroll
            for (int kk = 0; kk < 2; ++kk)
                pf[mf][kk] = *(const bf16x8*)&Ps[wave][mf * 16 + lm][kk * 32 + quad * 8];

        #pragma unroll
        for (int mf = 0; mf < 4; ++mf) {
            #pragma unroll
            for (int nt = 0; nt < 4; ++nt) {
                accO[mf][nt] = __builtin_amdgcn_mfma_f32_16x16x32_bf16(pf[mf][0], vf[nt][0], accO[mf][nt], 0, 0, 0);
                accO[mf][nt] = __builtin_amdgcn_mfma_f32_16x16x32_bf16(pf[mf][1], vf[nt][1], accO[mf][nt], 0, 0, 0);
            }
            accL[mf] = __builtin_amdgcn_mfma_f32_16x16x32_bf16(pf[mf][0], vf[4][0], accL[mf], 0, 0, 0);
            accL[mf] = __builtin_amdgcn_mfma_f32_16x16x32_bf16(pf[mf][1], vf[4][1], accL[mf], 0, 0, 0);
        }
    };

    load_k(t0k, kf0);
    for (int i = 0; i < 8; i += 2) {
        load_k(t0k + i + 1, kf1);
        process(t0k + i, kf0);
        load_k(t0k + ((i + 2) & 7), kf0);   // phantom wrap reload on last iter
        process(t0k + i + 1, kf1);
    }

    // exchange partial l across the 4 key-quarters (one barrier total)
    if (lm == 0) {
        #pragma unroll
        for (int mf = 0; mf < 4; ++mf)
            #pragma unroll
            for (int r = 0; r < 4; ++r)
                Lx[qh][ks][mf * 16 + quad * 4 + r] = accL[mf][r];
    }
    __syncthreads();

    // fused masked pooling with full l
    float pooled[4] = {0.f, 0.f, 0.f, 0.f};
    #pragma unroll
    for (int mf = 0; mf < 4; ++mf)
        #pragma unroll
        for (int r = 0; r < 4; ++r) {
            int rloc = mf * 16 + quad * 4 + r;
            float l = (Lx[qh][0][rloc] + Lx[qh][1][rloc]) +
                      (Lx[qh][2][rloc] + Lx[qh][3][rloc]);
            float w = (1.0f - kpmf[b_ * T + qbase + rloc]) / l;
            #pragma unroll
            for (int nt = 0; nt < 4; ++nt) pooled[nt] += accO[mf][nt][r] * w;
        }
    #pragma unroll
    for (int nt = 0; nt < 4; ++nt) {
        pooled[nt] += __shfl_xor(pooled[nt], 16, 64);
        pooled[nt] += __shfl_xor(pooled[nt], 32, 64);
    }
    if (quad == 0) {
        #pragma unroll
        for (int nt = 0; nt < 4; ++nt)
            atomicAdd(&S[b_ * D + h * DH + nt * 16 + lm], pooled[nt]);
    }
}

// ---------------- Kernel E: out-projection of pooled vector + bias ----------
__global__ __launch_bounds__(256) void out_kernel(
    const float* __restrict__ S, const float* __restrict__ kpmf,
    const float* __restrict__ Wo, const float* __restrict__ bo,
    float* __restrict__ out)
{
    __shared__ float Sl[512];
    __shared__ float cs[4];
    __shared__ float pr[4][64];
    int b_ = blockIdx.x >> 3;
    int cg = blockIdx.x & 7;
    int tid = threadIdx.x;
    int col = tid & 63, kq = tid >> 6;
    Sl[tid] = S[b_ * D + tid];
    Sl[tid + 256] = S[b_ * D + tid + 256];
    const float* kp = kpmf + b_ * T;
    float c = 0.f;
    for (int t = tid; t < T; t += 256) c += kp[t];
    #pragma unroll
    for (int o = 32; o; o >>= 1) c += __shfl_xor(c, o, 64);
    if ((tid & 63) == 0) cs[tid >> 6] = c;
    __syncthreads();
    float masked = cs[0] + cs[1] + cs[2] + cs[3];
    float cnt = (float)T - masked;
    float inv = 1.0f / fmaxf(cnt, 1.0f);

    int d = cg * 64 + col;
    const float4* wr4 = (const float4*)(Wo + (size_t)d * D + kq * 128);
    float dot = 0.f;
    #pragma unroll 8
    for (int i = 0; i < 32; ++i) {
        float4 w4 = wr4[i];
        int kbase = kq * 128 + i * 4;
        dot += Sl[kbase + 0] * w4.x + Sl[kbase + 1] * w4.y +
               Sl[kbase + 2] * w4.z + Sl[kbase + 3] * w4.w;
    }
    pr[kq][col] = dot;
    __syncthreads();
    if (kq == 0) {
        float tot = pr[0][col] + pr[1][col] + pr[2][col] + pr[3][col];
        out[b_ * D + d] = (tot + bo[d] * cnt) * inv;
    }
}

extern "C" void kernel_launch(void* const* d_in, const int* in_sizes, int n_in,
                              void* d_out, int out_size, void* d_ws, size_t ws_size,
                              hipStream_t stream) {
    const float* embs   = (const float*)d_in[0];
    const float* labels = (const float*)d_in[1];
    const float* ln_g   = (const float*)d_in[2];
    const float* ln_b   = (const float*)d_in[3];
    const float* ipw    = (const float*)d_in[4];
    const float* ipb    = (const float*)d_in[5];
    const float* ow     = (const float*)d_in[6];
    const float* obb    = (const float*)d_in[7];
    const float* alpha  = (const float*)d_in[8];
    const float* beta   = (const float*)d_in[9];
    float* out = (float*)d_out;

    unsigned short* xfrag  = (unsigned short*)d_ws;          // 8192*512
    unsigned short* wbfrag = xfrag + (size_t)NTOK * D;       // 1536*512
    unsigned short* qfrag  = wbfrag + (size_t)3 * D * D;     // 8192*512
    unsigned short* kfrag  = qfrag + (size_t)NTOK * D;       // 8192*512
    unsigned short* vfrag  = kfrag + (size_t)NTOK * D;       // 32*32*2*5*512
    float* wexp = (float*)(vfrag + (size_t)32 * 32 * 2 * 5 * 512);  // 8192
    float* kpmf = wexp + NTOK;                               // 8192
    float* S    = kpmf + NTOK;                               // 2048

    hipMemsetAsync(S, 0, (size_t)NB * D * sizeof(float), stream);
    prep_kernel<<<512 + 96, 256, 0, stream>>>(embs, labels, ln_g, ln_b, alpha, beta,
                                              ipw, xfrag, wbfrag, wexp, kpmf);
    dim3 gq(NTOK / 128, (3 * D) / 128);
    qkv_mfma<<<gq, 256, 0, stream>>>(xfrag, wbfrag, ipb, wexp, qfrag, kfrag, vfrag);
    attn_mfma<<<32 * (T / 128), 512, 0, stream>>>(qfrag, kfrag, vfrag, kpmf, S);
    out_kernel<<<NB * 8, 256, 0, stream>>>(S, kpmf, ow, obb, out);
}